// Round 7
// baseline (2685.658 us; speedup 1.0000x reference)
//
#include <hip/hip_runtime.h>

#define BB 4
#define NN 8192
#define SS 2048
#define KK 16

typedef float v2f __attribute__((ext_vector_type(2)));

// ---------------- FPS (R13 math) + folded transpose + spinners + R17: ballot-gated cached ladder ----------------
// R17. R6 post-mortem: launch gaps small; tail is real work; fps per-iter ~700cy vs ~600cy modeled critical
// path at effective ~0.9-1GHz. Remaining fps lever = per-SIMD ISSUE pressure: all 8 waves ran the ~100-instr
// bound+ladder every iter (~400 cy/SIMD issue). In pruned steady state most waves have NO updated lane ->
// their wave-max key is unchanged. Gate: if !__any(act), lane63 rewrites the CACHED key (exact: no lane's
// (dmax,beste) changed) and the u64-DPP ladder is skipped. Ladder, when run, covers all 64 lanes (inactive
// lanes' old dmax can still be the wave max). Cache init at it=1: all waves active (lb << 1e10). All other
// code byte-identical to R6 (verified 2417us; R4-equal within noise).
#define FTH 512
#define FPT (NN/FTH)  // 16 points per thread
#define TRB 256       // transpose blocks
#define SPB 124       // spinner blocks
__global__ __launch_bounds__(FTH, 1) void fps_kernel(
    const float* __restrict__ xyz,    // [B,3,N]
    const float* __restrict__ points, // [B,64,N]
    float* __restrict__ out_newxyz,   // [B,3,S]
    float* __restrict__ nxt,          // [B,S,3]
    float* __restrict__ ptst,         // [B,N,64]
    int* __restrict__ spin_flag)
{
  #pragma clang fp contract(off)
  const int blk = blockIdx.x;
  const int tid = threadIdx.x;
  __shared__ __align__(16) float4 sxyz[NN];                // 128 KB sorted points
  __shared__ __align__(16) unsigned long long skey[2][8];  // per-wave packed (maxdist,~idx), dbuf
  __shared__ int smi[SS];                                  // scan scratch / winner history
  __shared__ float sred[8*6];                              // per-wave bbox partials
  __shared__ float tile[32][33];                           // transpose-role tile

  if (blk >= BB) {
    if (blk < BB + TRB) {
      // ---------- transpose role: points [B,64,N] -> ptst [B,N,64], 8 tiles of 32x32 ----------
      if (blk == BB && tid == 0) spin_flag[8] = 0;         // zero bn-fusion counter (pre-bn_partial by stream order)
      const int x = tid & 31, yy = tid >> 5;               // 32 x 16
      for (int q = 0; q < 8; ++q) {
        const int tj = (blk - BB)*8 + q;                   // [0, 2048)
        const int tn = tj & 255, tc = (tj >> 8) & 1, tb = tj >> 9;
        const int n0 = tn*32, c0 = tc*32;
        __syncthreads();
        tile[yy][x]    = points[(tb*64 + c0+yy)*NN + n0+x];
        tile[yy+16][x] = points[(tb*64 + c0+yy+16)*NN + n0+x];
        __syncthreads();
        ptst[(tb*NN + n0+yy)*64 + c0+x]    = tile[x][yy];
        ptst[(tb*NN + n0+yy+16)*64 + c0+x] = tile[x][yy+16];
      }
      return;
    }
    // ---------- spinner role: wave 0 only; FMA activity; exit on fps done ----------
    if (tid >= 64) return;
    const int s0 = atomicAdd(spin_flag, 0);
    float a0 = 1.0f + tid, a1 = 2.0f, a2 = 3.0f, a3 = 4.0f;
    for (int outer = 0; outer < 50000; ++outer) {
      #pragma unroll
      for (int u = 0; u < 256; ++u) {
        a0 = fmaf(a0, 1.0000001f, 1e-7f);
        a1 = fmaf(a1, 0.9999999f, 2e-7f);
        a2 = fmaf(a2, 1.0000002f, 3e-7f);
        a3 = fmaf(a3, 0.9999998f, 4e-7f);
      }
      if (atomicAdd(spin_flag, 0) - s0 >= BB) break;
    }
    asm volatile("" :: "v"(a0), "v"(a1), "v"(a2), "v"(a3));
    return;
  }

  // ---------------- fps role: EXACT R13 structure ----------------
  const int b = blk;
  const int wave = tid >> 6;
  const int lane = tid & 63;
  const float* xb = xyz + b*3*NN;

  // ---- S1: load my 16 points (coalesced) ----
  float tx[FPT], ty[FPT], tz[FPT];
  #pragma unroll
  for (int j = 0; j < FPT; ++j) {
    int i = tid + j*FTH;
    tx[j] = xb[i]; ty[j] = xb[NN+i]; tz[j] = xb[2*NN+i];
  }
  // ---- S2: block bbox (DPP wave reduce; 0-fill only widens bbox -> perf-only, never wrong) ----
  float mnx = tx[0], mxx = tx[0], mny = ty[0], mxy = ty[0], mnz = tz[0], mxz = tz[0];
  #pragma unroll
  for (int j = 1; j < FPT; ++j) {
    mnx = fminf(mnx, tx[j]); mxx = fmaxf(mxx, tx[j]);
    mny = fminf(mny, ty[j]); mxy = fmaxf(mxy, ty[j]);
    mnz = fminf(mnz, tz[j]); mxz = fmaxf(mxz, tz[j]);
  }
  #define WRED(var, OP) { \
    float s_; \
    s_ = __int_as_float(__builtin_amdgcn_update_dpp(0, __float_as_int(var), 0x111, 0xf, 0xf, true)); var = OP(var, s_); \
    s_ = __int_as_float(__builtin_amdgcn_update_dpp(0, __float_as_int(var), 0x112, 0xf, 0xf, true)); var = OP(var, s_); \
    s_ = __int_as_float(__builtin_amdgcn_update_dpp(0, __float_as_int(var), 0x114, 0xf, 0xf, true)); var = OP(var, s_); \
    s_ = __int_as_float(__builtin_amdgcn_update_dpp(0, __float_as_int(var), 0x118, 0xf, 0xf, true)); var = OP(var, s_); \
    s_ = __int_as_float(__builtin_amdgcn_update_dpp(0, __float_as_int(var), 0x142, 0xf, 0xf, true)); var = OP(var, s_); \
    s_ = __int_as_float(__builtin_amdgcn_update_dpp(0, __float_as_int(var), 0x143, 0xf, 0xf, true)); var = OP(var, s_); }
  WRED(mnx, fminf) WRED(mxx, fmaxf) WRED(mny, fminf) WRED(mxy, fmaxf) WRED(mnz, fminf) WRED(mxz, fmaxf)
  #undef WRED
  if (lane == 63) {
    sred[wave*6+0] = mnx; sred[wave*6+1] = mxx; sred[wave*6+2] = mny;
    sred[wave*6+3] = mxy; sred[wave*6+4] = mnz; sred[wave*6+5] = mxz;
  }
  smi[tid] = 0;                       // zero hist region [0,512)
  __syncthreads();
  #pragma unroll
  for (int w = 0; w < 8; ++w) {
    mnx = fminf(mnx, sred[w*6+0]); mxx = fmaxf(mxx, sred[w*6+1]);
    mny = fminf(mny, sred[w*6+2]); mxy = fmaxf(mxy, sred[w*6+3]);
    mnz = fminf(mnz, sred[w*6+4]); mxz = fmaxf(mxz, sred[w*6+5]);
  }
  const float scx = 8.0f / (mxx - mnx + 1e-12f);
  const float scy = 8.0f / (mxy - mny + 1e-12f);
  const float scz = 8.0f / (mxz - mnz + 1e-12f);
  // ---- S3: histogram by Morton cell ----
  int cells[FPT];
  #pragma unroll
  for (int j = 0; j < FPT; ++j) {
    int qx = min(7, (int)((tx[j] - mnx) * scx));
    int qy = min(7, (int)((ty[j] - mny) * scy));
    int qz = min(7, (int)((tz[j] - mnz) * scz));
    int m = (qx&1) | ((qy&1)<<1) | ((qz&1)<<2)
          | ((qx&2)<<2) | ((qy&2)<<3) | ((qz&2)<<4)
          | ((qx&4)<<4) | ((qy&4)<<5) | ((qz&4)<<6);
    cells[j] = m;
    atomicAdd(&smi[m], 1);
  }
  __syncthreads();
  // ---- S4: inclusive scan over smi[0..511] (Hillis-Steele), exclusive cursors in smi[512..1023] ----
  for (int d = 1; d < 512; d <<= 1) {
    int v = smi[tid];
    int a = (tid >= d) ? smi[tid - d] : 0;
    __syncthreads();
    smi[tid] = v + a;
    __syncthreads();
  }
  {
    int excl = (tid == 0) ? 0 : smi[tid - 1];
    smi[512 + tid] = excl;
  }
  __syncthreads();
  // ---- S5: scatter into sorted order ----
  #pragma unroll
  for (int j = 0; j < FPT; ++j) {
    int pos = atomicAdd(&smi[512 + cells[j]], 1);
    sxyz[pos] = make_float4(tx[j], ty[j], tz[j], 0.0f);
  }
  __syncthreads();
  // ---- S6: reload my contiguous chunk [tid*16, tid*16+16), AABB, dist init ----
  v2f px[FPT/2], py[FPT/2], pz[FPT/2], dist[FPT/2];
  float bx0, bx1, by0, by1, bz0, bz1;
  {
    float4 c0 = sxyz[tid*FPT];
    bx0 = bx1 = c0.x; by0 = by1 = c0.y; bz0 = bz1 = c0.z;
    #pragma unroll
    for (int e = 0; e < FPT; ++e) {
      float4 cc = sxyz[tid*FPT + e];
      ((float*)px)[e] = cc.x; ((float*)py)[e] = cc.y; ((float*)pz)[e] = cc.z;
      ((float*)dist)[e] = 1e10f;
      bx0 = fminf(bx0, cc.x); bx1 = fmaxf(bx1, cc.x);
      by0 = fminf(by0, cc.y); by1 = fmaxf(by1, cc.y);
      bz0 = fminf(bz0, cc.z); bz1 = fmaxf(bz1, cc.z);
    }
  }
  float dmax = 1e10f;
  int   beste = 0;
  unsigned kc_hi = 0, kc_lo = 0;      // cached post-ladder wave-max key (valid from it=1 on)
  float cx = xb[0], cy = xb[NN], cz = xb[2*NN];   // iteration-0 centroid = ORIGINAL point 0
  __syncthreads();
  // ---- main serial loop ----
  for (int it = 1; it < SS; ++it) {
    const int buf = it & 1;
    float gx = fmaxf(fmaxf(bx0 - cx, cx - bx1), 0.0f);
    float gy = fmaxf(fmaxf(by0 - cy, cy - by1), 0.0f);
    float gz = fmaxf(fmaxf(bz0 - cz, cz - bz1), 0.0f);
    float lb = gx*gx + gy*gy; lb = lb + gz*gz;
    const bool act = lb * 0.99999f < dmax;
    // wave-uniform gate: if no lane updated, the wave-max key is unchanged -> reuse cache, skip ladder
    if (__any(act)) {
      if (act) {
        v2f cx2 = {cx, cx}, cy2 = {cy, cy}, cz2 = {cz, cz};
        v2f vmax = {-1.0f, -1.0f};
        #pragma unroll
        for (int j = 0; j < FPT/2; ++j) {
          v2f dx = px[j] - cx2, dy = py[j] - cy2, dz = pz[j] - cz2;
          v2f d = dx*dx + dy*dy;
          d = d + dz*dz;
          v2f nd = __builtin_elementwise_min(dist[j], d);
          dist[j] = nd;
          vmax = __builtin_elementwise_max(vmax, nd);
        }
        float mloc = fmaxf(vmax.x, vmax.y);
        int ce[FPT/2];
        #pragma unroll
        for (int j = 0; j < FPT/2; ++j) {
          int c = 0x7FFFFFFF;
          if (dist[j].y == mloc) c = 2*j + 1;
          if (dist[j].x == mloc) c = 2*j;
          ce[j] = c;
        }
        #pragma unroll
        for (int st = FPT/4; st >= 1; st >>= 1) {
          #pragma unroll
          for (int j = 0; j < st; ++j) ce[j] = ce[j] < ce[j+st] ? ce[j] : ce[j+st];
        }
        dmax = mloc;
        beste = ce[0];
      }
      // ladder over ALL lanes of this wave (inactive lanes' old keys can still be the wave max)
      unsigned khi = __float_as_uint(dmax);
      unsigned klo = ~(unsigned)((tid << 4) + beste);
      #define FPS_RED(ctrl) { \
        unsigned nlo = (unsigned)__builtin_amdgcn_update_dpp(0, (int)klo, ctrl, 0xf, 0xf, true); \
        unsigned nhi = (unsigned)__builtin_amdgcn_update_dpp(0, (int)khi, ctrl, 0xf, 0xf, true); \
        unsigned long long nk = ((unsigned long long)nhi << 32) | nlo; \
        unsigned long long ck = ((unsigned long long)khi << 32) | klo; \
        if (nk > ck) { khi = nhi; klo = nlo; } }
      FPS_RED(0x111)
      FPS_RED(0x112)
      FPS_RED(0x114)
      FPS_RED(0x118)
      FPS_RED(0x142)
      FPS_RED(0x143)
      #undef FPS_RED
      kc_hi = khi; kc_lo = klo;
    }
    if (lane == 63) skey[buf][wave] = ((unsigned long long)kc_hi << 32) | kc_lo;
    __syncthreads();
    const ulonglong2* kp = (const ulonglong2*)&skey[buf][0];
    ulonglong2 k01 = kp[0], k23 = kp[1], k45 = kp[2], k67 = kp[3];
    unsigned long long m0 = k01.x > k01.y ? k01.x : k01.y;
    unsigned long long m1 = k23.x > k23.y ? k23.x : k23.y;
    unsigned long long m2 = k45.x > k45.y ? k45.x : k45.y;
    unsigned long long m3 = k67.x > k67.y ? k67.x : k67.y;
    unsigned long long ma = m0 > m1 ? m0 : m1;
    unsigned long long mb = m2 > m3 ? m2 : m3;
    unsigned long long mk = ma > mb ? ma : mb;
    int mi = (int)(~(unsigned)mk);
    float4 c = sxyz[mi];
    if (tid == 0) smi[it] = mi;
    cx = c.x; cy = c.y; cz = c.z;
  }
  __syncthreads();
  // epilogue: it=0 from ORIGINAL point 0; others from sorted winner history
  for (int it = tid; it < SS; it += FTH) {
    float x, y, z;
    if (it == 0) { x = xb[0]; y = xb[NN]; z = xb[2*NN]; }
    else { float4 c = sxyz[smi[it]]; x = c.x; y = c.y; z = c.z; }
    out_newxyz[(b*3+0)*SS + it] = x;
    out_newxyz[(b*3+1)*SS + it] = y;
    out_newxyz[(b*3+2)*SS + it] = z;
    nxt[(b*SS+it)*3+0] = x; nxt[(b*SS+it)*3+1] = y; nxt[(b*SS+it)*3+2] = z;
  }
  if (tid == 0) atomicAdd(spin_flag, 1);   // release spinners
}

// ---------------- KNN fused, 512 thr = 8 waves; each wave scans 1/8; 8-way stable merge ----------------
#define TILE 2048
#define KTH 512
__global__ __launch_bounds__(KTH) void knn_kernel(
    const float* __restrict__ query_t, // [B,S,3]
    const float* __restrict__ cand1,   // [B,3,NN]
    const float* __restrict__ cand2,   // [B,3,SS]
    int* __restrict__ out1,            // [B,S,K]
    int* __restrict__ out2)            // [B,S,K]
{
  #pragma clang fp contract(off)
  __shared__ float4 sc[TILE];            // 32 KB
  __shared__ float  smd[8*64*17];        // per-wave top-16 dists (pad 17) ~34.8 KB
  __shared__ int    smj[8*64*17];        // per-wave top-16 idxs
  const int blocksPerB = SS/64;          // 32
  const int half = blockIdx.x >> 7;      // 0: vs xyz, 1: self
  const int blk = blockIdx.x & 127;
  const float* cand = half ? cand2 : cand1;
  const int Nc = half ? SS : NN;
  int* outidx = half ? out2 : out1;
  const int b = blk / blocksPerB;
  const int q0 = (blk % blocksPerB)*64;
  const int wave = threadIdx.x >> 6, lane = threadIdx.x & 63;
  const int s = q0 + lane;
  const float qx = query_t[(b*SS+s)*3+0];
  const float qy = query_t[(b*SS+s)*3+1];
  const float qz = query_t[(b*SS+s)*3+2];
  float sq = qx*qx + qy*qy; sq = sq + qz*qz;
  float d16[16]; int i16[16];
  #pragma unroll
  for (int j = 0; j < 16; ++j) { d16[j] = 1e30f; i16[j] = 0x7FFFFFFF; }
  const float* cb = cand + b*3*Nc;
  const int QL = TILE/8;                 // 256 candidates per wave per tile
  for (int base = 0; base < Nc; base += TILE) {
    __syncthreads();
    for (int j = threadIdx.x; j < TILE; j += KTH) {
      float x = cb[base+j], y = cb[Nc+base+j], z = cb[2*Nc+base+j];
      float pp = x*x + y*y; pp = pp + z*z;
      sc[j] = make_float4(x, y, z, pp);
    }
    __syncthreads();
    const int lo = wave*QL, hi = lo + QL;
    for (int j = lo; j < hi; ++j) {
      float4 c = sc[j];
      float qp = qx*c.x + qy*c.y; qp = qp + qz*c.z;
      float d2 = (sq + c.w) - 2.0f*qp;
      if (d2 < d16[15]) {
        d16[15] = d2; i16[15] = base + j;
        #pragma unroll
        for (int t = 15; t > 0; --t) {
          if (d16[t] < d16[t-1]) {
            float td = d16[t]; d16[t] = d16[t-1]; d16[t-1] = td;
            int   ti = i16[t]; i16[t] = i16[t-1]; i16[t-1] = ti;
          }
        }
      }
    }
  }
  const int off = (wave*64 + lane)*17;
  #pragma unroll
  for (int j = 0; j < 16; ++j) { smd[off+j] = d16[j]; smj[off+j] = i16[j]; }
  __syncthreads();
  if (wave == 0) {
    // 8-way stable merge: tie-break on smaller index = stable lax.top_k semantics
    int p[8] = {0,0,0,0,0,0,0,0};
    for (int o = 0; o < 16; ++o) {
      float bd = 3e38f; int bi = 0x7FFFFFFF, bw = 0;
      #pragma unroll
      for (int w = 0; w < 8; ++w) {
        float d = smd[(w*64+lane)*17 + p[w]];
        int   i = smj[(w*64+lane)*17 + p[w]];
        if (d < bd || (d == bd && i < bi)) { bd = d; bi = i; bw = w; }
      }
      p[bw]++;
      outidx[(b*SS+s)*KK + o] = bi;
    }
  }
}

// ---------------- Transition-down conv + stats + max over K (ptst gather, coalesced) ----------------
__global__ __launch_bounds__(128) void td_kernel(
    const float* __restrict__ ptst,    // [B,N,64] point-major
    const float* __restrict__ xyz,     // [B,3,N]
    const float* __restrict__ newxyz,  // [B,3,S]
    const int* __restrict__ gidx,      // [B,S,K]
    const float* __restrict__ td_w,    // [128,67]
    const float* __restrict__ td_b,    // [128]
    float* __restrict__ ymax,          // [B*S,128]
    float* __restrict__ psum,          // [B*S,128]
    float* __restrict__ psq)
{
  const int bs = blockIdx.x;
  const int b = bs >> 11, s = bs & (SS-1);
  const int t = threadIdx.x;
  __shared__ int gi[KK];
  __shared__ float g[67*17];           // stride 17: conflict-free writes
  if (t < KK) gi[t] = gidx[bs*KK + t];
  __syncthreads();
  // features 0..63: per neighbor, 64 consecutive floats (coalesced 256B rows)
  #pragma unroll
  for (int base = 0; base < 1024; base += 128) {
    int idx = base + t;
    int i = idx & 63, k = idx >> 6;
    g[i*17 + k] = ptst[(b*NN + gi[k])*64 + i];
  }
  // xyz channels 64..66 (48 scattered reads)
  if (t < 48) {
    int c = t >> 4, k = t & 15;
    g[(64+c)*17 + k] = xyz[(b*3+c)*NN + gi[k]] - newxyz[(b*3+c)*SS + s];
  }
  __syncthreads();
  float acc[KK];
  #pragma unroll
  for (int k = 0; k < KK; ++k) acc[k] = 0.0f;
  const float* wrow = td_w + t*67;
  for (int i = 0; i < 67; ++i) {
    float w = wrow[i];
    #pragma unroll
    for (int k = 0; k < KK; ++k) acc[k] = fmaf(w, g[i*17 + k], acc[k]);
  }
  float bias = td_b[t];
  float mx = -1e30f, s1 = 0.f, s2 = 0.f;
  #pragma unroll
  for (int k = 0; k < KK; ++k) {
    float y = acc[k] + bias;
    mx = fmaxf(mx, y);
    s1 += y;
    s2 = fmaf(y, y, s2);
  }
  ymax[bs*128 + t] = mx;             // coalesced
  psum[bs*128 + t] = s1;             // coalesced
  psq [bs*128 + t] = s2;             // coalesced
}

// ---------------- bn_partial + fused bn_final (last-block trick; counter zeroed by fps launch) ----------------
__global__ __launch_bounds__(256) void bn_partial(
    const float* __restrict__ psum, const float* __restrict__ psq,
    float* __restrict__ part1, float* __restrict__ part2,
    const float* __restrict__ gamma, const float* __restrict__ beta,
    float* __restrict__ scale, float* __restrict__ bias,
    int* __restrict__ counter)
{
  const int blk = blockIdx.x, t = threadIdx.x;
  const int c = t & 127, half = t >> 7;
  const float* ps = psum + (blk*64 + half*32)*128;
  const float* pq = psq  + (blk*64 + half*32)*128;
  float s1 = 0.f, s2 = 0.f;
  for (int r = 0; r < 32; ++r) { s1 += ps[r*128 + c]; s2 += pq[r*128 + c]; }
  __shared__ float sh1[256], sh2[256];
  __shared__ int s_last;
  sh1[t] = s1; sh2[t] = s2;
  __syncthreads();
  if (t < 128) {
    part1[blk*128 + t] = sh1[t] + sh1[t+128];
    part2[blk*128 + t] = sh2[t] + sh2[t+128];
  }
  // release: make part writes visible, then count this block done
  __syncthreads();
  __threadfence();
  if (t == 0) s_last = (atomicAdd(counter, 1) == 127) ? 1 : 0;
  __syncthreads();
  if (!s_last) return;
  __threadfence();    // acquire: all other blocks' part writes now visible
  // final reduce: thread t handles channel c over half the 128 part rows
  float f1 = 0.f, f2 = 0.f;
  for (int j = half*64; j < half*64 + 64; ++j) {
    f1 += part1[j*128 + c];
    f2 += part2[j*128 + c];
  }
  sh1[t] = f1; sh2[t] = f2;
  __syncthreads();
  if (t < 128) {
    float a1 = sh1[t] + sh1[t+128];
    float a2 = sh2[t] + sh2[t+128];
    const float n = (float)(BB*SS*KK);
    float mean = a1/n;
    float var  = a2/n - mean*mean;
    float sc = gamma[t] / sqrtf(var + 1e-5f);
    scale[t] = sc;
    bias[t]  = beta[t] - mean*sc;
  }
}

// ---------------- r1_first: fused td_final + r1 (i=0) ----------------
__global__ __launch_bounds__(128) void r1_first(
    const float* __restrict__ ymax,   // [B*S,128]
    const float* __restrict__ scale, const float* __restrict__ bias,
    const float* __restrict__ bw, const float* __restrict__ bb,   // [32,128],[32]
    const float* __restrict__ qw,                                 // [96,32]
    float* __restrict__ pts,          // [B*S,128] (written here)
    float* __restrict__ qkv)
{
  const int bs = blockIdx.x;
  const int t = threadIdx.x;
  __shared__ float pcol[128];
  __shared__ float p[32];
  float v = fmaxf(fmaf(ymax[bs*128 + t], scale[t], bias[t]), 0.0f);
  pts[bs*128 + t] = v;               // materialize pts for r2's residual +=
  pcol[t] = v;
  __syncthreads();
  if (t < 32) {
    float acc = 0.f;
    const float* w = bw + t*128;
    for (int j = 0; j < 128; ++j) acc = fmaf(w[j], pcol[j], acc);
    p[t] = acc + bb[t];
  }
  __syncthreads();
  if (t < 96) {
    float acc = 0.f;
    const float* w = qw + t*32;
    #pragma unroll
    for (int j = 0; j < 32; ++j) acc = fmaf(w[j], p[j], acc);
    qkv[bs*96 + t] = acc;            // coalesced
  }
}

// ---------------- Res block part 1 (pts [B*S,128], qkv [B*S,96]) ----------------
__global__ __launch_bounds__(128) void r1_kernel(
    const float* __restrict__ pts,
    const float* __restrict__ bw, const float* __restrict__ bb,   // [32,128],[32]
    const float* __restrict__ qw,                                 // [96,32]
    float* __restrict__ qkv)
{
  const int bs = blockIdx.x;
  const int t = threadIdx.x;
  __shared__ float pcol[128];
  __shared__ float p[32];
  pcol[t] = pts[bs*128 + t];           // coalesced
  __syncthreads();
  if (t < 32) {
    float acc = 0.f;
    const float* w = bw + t*128;
    for (int j = 0; j < 128; ++j) acc = fmaf(w[j], pcol[j], acc);
    p[t] = acc + bb[t];
  }
  __syncthreads();
  if (t < 96) {
    float acc = 0.f;
    const float* w = qw + t*32;
    #pragma unroll
    for (int j = 0; j < 32; ++j) acc = fmaf(w[j], p[j], acc);
    qkv[bs*96 + t] = acc;              // coalesced
  }
}

// ---------------- Res block part 2; outT!=null => write final transposed to [B,128,S] (skip pts) ----------------
__global__ __launch_bounds__(128) void r2_kernel(
    const float* __restrict__ qkv,
    const float* __restrict__ newxyz, // [B,3,S]
    const int* __restrict__ sgidx,    // [B,S,K]
    const float* __restrict__ pw1, const float* __restrict__ pb1,  // [64,3],[64]
    const float* __restrict__ pw2, const float* __restrict__ pb2,  // [32,64],[32]
    const float* __restrict__ aw1, const float* __restrict__ ab1,  // [128,32],[128]
    const float* __restrict__ aw2, const float* __restrict__ ab2,  // [32,128],[32]
    const float* __restrict__ fw,  const float* __restrict__ fb,   // [128,32],[128]
    float* __restrict__ pts,          // [B*S,128]  (+= when outT==null)
    float* __restrict__ outT)         // [B,128,S] or null
{
  const int bs = blockIdx.x;
  const int b = bs >> 11, s = bs & (SS-1);
  const int t = threadIdx.x;
  __shared__ int sgi[KK];
  __shared__ float qv[32];
  __shared__ float kn[32*17], vn[32*17];   // stride 17: conflict-free
  __shared__ float gx[3*KK];
  __shared__ float h1[64*KK];
  __shared__ float x2[32*KK];
  __shared__ float a1[128*17];             // stride 17: kills 16-way write conflicts
  __shared__ float simb[32*KK];
  __shared__ float agg[32];
  if (t < KK) sgi[t] = sgidx[bs*KK + t];
  __syncthreads();
  if (t < 32) qv[t] = qkv[bs*96 + t];
  // c-major gather: each wave reads 2 neighbor rows x 32 consecutive floats (coalesced)
  for (int idx = t; idx < 32*KK; idx += 128) {
    int k = idx >> 5, c = idx & 31;
    int base = (b*SS + sgi[k])*96;
    kn[c*17+k] = qkv[base + 32 + c];
    vn[c*17+k] = qkv[base + 64 + c];
  }
  if (t < 3*KK) {
    int c = t >> 4, k = t & 15;
    gx[t] = newxyz[(b*3+c)*SS + s] - newxyz[(b*3+c)*SS + sgi[k]];
  }
  __syncthreads();
  for (int idx = t; idx < 64*KK; idx += 128) {
    int c = idx >> 4, k = idx & 15;
    float acc = 0.f;
    #pragma unroll
    for (int j = 0; j < 3; ++j) acc = fmaf(pw1[c*3+j], gx[j*KK+k], acc);
    h1[idx] = fmaxf(acc + pb1[c], 0.0f);
  }
  __syncthreads();
  for (int idx = t; idx < 32*KK; idx += 128) {
    int c = idx >> 4, k = idx & 15;
    float acc = 0.f;
    const float* w = pw2 + c*64;
    for (int j = 0; j < 64; ++j) acc = fmaf(w[j], h1[j*KK+k], acc);
    float r = acc + pb2[c];
    x2[idx] = (qv[c] - kn[c*17+k]) + r;   // qk_rel + rel
    vn[c*17+k] = vn[c*17+k] + r;          // v + rel
  }
  __syncthreads();
  {
    float acc[KK];
    #pragma unroll
    for (int k = 0; k < KK; ++k) acc[k] = 0.f;
    const float* w = aw1 + t*32;
    for (int j = 0; j < 32; ++j) {
      float wv = w[j];
      #pragma unroll
      for (int k = 0; k < KK; ++k) acc[k] = fmaf(wv, x2[j*KK+k], acc[k]);
    }
    float bv = ab1[t];
    #pragma unroll
    for (int k = 0; k < KK; ++k) a1[t*17+k] = fmaxf(acc[k] + bv, 0.0f);
  }
  __syncthreads();
  for (int idx = t; idx < 32*KK; idx += 128) {
    int c = idx >> 4, k = idx & 15;
    float acc = 0.f;
    const float* w = aw2 + c*128;
    for (int j = 0; j < 128; ++j) acc = fmaf(w[j], a1[j*17+k], acc);
    simb[idx] = acc + ab2[c];
  }
  __syncthreads();
  if (t < 32) {
    float m = -1e30f;
    #pragma unroll
    for (int k = 0; k < KK; ++k) m = fmaxf(m, simb[t*KK+k]);
    float sum = 0.f;
    float e[KK];
    #pragma unroll
    for (int k = 0; k < KK; ++k) { e[k] = __expf(simb[t*KK+k] - m); sum += e[k]; }
    float inv = 1.0f / sum;
    float a = 0.f;
    #pragma unroll
    for (int k = 0; k < KK; ++k) a = fmaf(e[k]*inv, vn[t*17+k], a);
    agg[t] = a;
  }
  __syncthreads();
  {
    float acc = 0.f;
    const float* w = fw + t*32;
    #pragma unroll
    for (int j = 0; j < 32; ++j) acc = fmaf(w[j], agg[j], acc);
    float val = pts[bs*128 + t] + (acc + fb[t]);
    if (outT) outT[(b*128 + t)*SS + s] = val;    // final layer: direct transposed store
    else      pts[bs*128 + t] = val;             // coalesced
  }
}

extern "C" void kernel_launch(void* const* d_in, const int* in_sizes, int n_in,
                              void* d_out, int out_size, void* d_ws, size_t ws_size,
                              hipStream_t stream) {
  const float* xyz      = (const float*)d_in[0];
  const float* points   = (const float*)d_in[1];
  const float* td_w     = (const float*)d_in[2];
  const float* td_b     = (const float*)d_in[3];
  const float* td_gamma = (const float*)d_in[4];
  const float* td_beta  = (const float*)d_in[5];
  const float* bw  = (const float*)d_in[6];
  const float* bb  = (const float*)d_in[7];
  const float* qw  = (const float*)d_in[8];
  const float* pw1 = (const float*)d_in[9];
  const float* pb1 = (const float*)d_in[10];
  const float* pw2 = (const float*)d_in[11];
  const float* pb2 = (const float*)d_in[12];
  const float* aw1 = (const float*)d_in[13];
  const float* ab1 = (const float*)d_in[14];
  const float* aw2 = (const float*)d_in[15];
  const float* ab2 = (const float*)d_in[16];
  const float* fw  = (const float*)d_in[17];
  const float* fb  = (const float*)d_in[18];
  float* out = (float*)d_out;
  float* out_newxyz = out;                 // [B,3,S]
  float* out_pts    = out + BB*3*SS;       // [B,128,S]

  char* w = (char*)d_ws;
  float* nxt    = (float*)w; w += BB*SS*3*sizeof(float);
  int*   gidx   = (int*)w;   w += BB*SS*KK*sizeof(int);
  int*   sgidx  = (int*)w;   w += BB*SS*KK*sizeof(int);
  float* ymax   = (float*)w; w += BB*128*SS*sizeof(float);
  float* psum   = (float*)w; w += 128*BB*SS*sizeof(float);
  float* psq    = (float*)w; w += 128*BB*SS*sizeof(float);
  float* part1  = (float*)w; w += 128*128*sizeof(float);
  float* part2  = (float*)w; w += 128*128*sizeof(float);
  float* bnscale= (float*)w; w += 256*sizeof(float);
  float* bnbias = (float*)w; w += 256*sizeof(float);
  float* pts    = (float*)w; w += BB*128*SS*sizeof(float);
  float* qkv    = (float*)w; w += BB*96*SS*sizeof(float);
  float* ptst   = (float*)w; w += BB*NN*64*sizeof(float);   // [B,N,64]
  int*   flags  = (int*)w;   w += 256;   // [0]=spinner release, [8]=bn counter (zeroed by fps launch)

  fps_kernel<<<BB + TRB + SPB, FTH, 0, stream>>>(xyz, points, out_newxyz, nxt, ptst, flags);
  knn_kernel<<<2*BB*(SS/64), KTH, 0, stream>>>(nxt, xyz, out_newxyz, gidx, sgidx);
  td_kernel<<<BB*SS, 128, 0, stream>>>(ptst, xyz, out_newxyz, gidx, td_w, td_b, ymax, psum, psq);
  bn_partial<<<128, 256, 0, stream>>>(psum, psq, part1, part2,
      td_gamma, td_beta, bnscale, bnbias, &flags[8]);
  // i = 0: r1 fused with td_final (writes pts from ymax)
  r1_first<<<BB*SS, 128, 0, stream>>>(ymax, bnscale, bnbias, bw, bb, qw, pts, qkv);
  r2_kernel<<<BB*SS, 128, 0, stream>>>(qkv, out_newxyz, sgidx,
      pw1, pb1, pw2, pb2, aw1, ab1, aw2, ab2, fw, fb, pts, nullptr);
  // i = 1: final r2 writes directly to out_pts transposed (transpose_out folded in)
  r1_kernel<<<BB*SS, 128, 0, stream>>>(pts, bw + 32*128, bb + 32, qw + 96*32, qkv);
  r2_kernel<<<BB*SS, 128, 0, stream>>>(qkv, out_newxyz, sgidx,
      pw1 + 64*3, pb1 + 64, pw2 + 32*64, pb2 + 32,
      aw1 + 128*32, ab1 + 128, aw2 + 32*128, ab2 + 32,
      fw + 128*32, fb + 128, pts, out_pts);
}

// Round 8
// 2400.694 us; speedup vs baseline: 1.1187x; 1.1187x over previous
//
#include <hip/hip_runtime.h>

#define BB 4
#define NN 8192
#define SS 2048
#define KK 16

typedef float v2f __attribute__((ext_vector_type(2)));

// ---------------- FPS (R13 math) + folded transpose + spinners; R18: short f32+ballot wave argmax ----------------
// R18. R17 post-mortem: gating/caching the ladder REGRESSED 17% -> per-iter time = winner-wave path +
// fixed tail; additions there cost 1:1, savings on idle waves are invisible (they wait at the barrier).
// Inverse move: shorten the unconditional path. u64 DPP ladder (54 instr) -> f32-max DPP ladder (12) +
// readlane(63) bcast + ballot(dmax==wm) + ffs + readlane(idx) ~= 20 instr. Tie semantics identical:
// (tid<<4)+beste strictly increasing in lane => lowest matching lane = smallest index = u64 max(~idx);
// fmax/DPP propagate operand bits so == is exact. skey format + block tree unchanged. Rest = R6 verbatim
// (verified 2417us): per-lane AABB-pruned update, bn fusion, transposed final store, spinners.
#define FTH 512
#define FPT (NN/FTH)  // 16 points per thread
#define TRB 256       // transpose blocks
#define SPB 124       // spinner blocks
__global__ __launch_bounds__(FTH, 1) void fps_kernel(
    const float* __restrict__ xyz,    // [B,3,N]
    const float* __restrict__ points, // [B,64,N]
    float* __restrict__ out_newxyz,   // [B,3,S]
    float* __restrict__ nxt,          // [B,S,3]
    float* __restrict__ ptst,         // [B,N,64]
    int* __restrict__ spin_flag)
{
  #pragma clang fp contract(off)
  const int blk = blockIdx.x;
  const int tid = threadIdx.x;
  __shared__ __align__(16) float4 sxyz[NN];                // 128 KB sorted points
  __shared__ __align__(16) unsigned long long skey[2][8];  // per-wave packed (maxdist,~idx), dbuf
  __shared__ int smi[SS];                                  // scan scratch / winner history
  __shared__ float sred[8*6];                              // per-wave bbox partials
  __shared__ float tile[32][33];                           // transpose-role tile

  if (blk >= BB) {
    if (blk < BB + TRB) {
      // ---------- transpose role: points [B,64,N] -> ptst [B,N,64], 8 tiles of 32x32 ----------
      if (blk == BB && tid == 0) spin_flag[8] = 0;         // zero bn-fusion counter (pre-bn_partial by stream order)
      const int x = tid & 31, yy = tid >> 5;               // 32 x 16
      for (int q = 0; q < 8; ++q) {
        const int tj = (blk - BB)*8 + q;                   // [0, 2048)
        const int tn = tj & 255, tc = (tj >> 8) & 1, tb = tj >> 9;
        const int n0 = tn*32, c0 = tc*32;
        __syncthreads();
        tile[yy][x]    = points[(tb*64 + c0+yy)*NN + n0+x];
        tile[yy+16][x] = points[(tb*64 + c0+yy+16)*NN + n0+x];
        __syncthreads();
        ptst[(tb*NN + n0+yy)*64 + c0+x]    = tile[x][yy];
        ptst[(tb*NN + n0+yy+16)*64 + c0+x] = tile[x][yy+16];
      }
      return;
    }
    // ---------- spinner role: wave 0 only; FMA activity; exit on fps done ----------
    if (tid >= 64) return;
    const int s0 = atomicAdd(spin_flag, 0);
    float a0 = 1.0f + tid, a1 = 2.0f, a2 = 3.0f, a3 = 4.0f;
    for (int outer = 0; outer < 50000; ++outer) {
      #pragma unroll
      for (int u = 0; u < 256; ++u) {
        a0 = fmaf(a0, 1.0000001f, 1e-7f);
        a1 = fmaf(a1, 0.9999999f, 2e-7f);
        a2 = fmaf(a2, 1.0000002f, 3e-7f);
        a3 = fmaf(a3, 0.9999998f, 4e-7f);
      }
      if (atomicAdd(spin_flag, 0) - s0 >= BB) break;
    }
    asm volatile("" :: "v"(a0), "v"(a1), "v"(a2), "v"(a3));
    return;
  }

  // ---------------- fps role: EXACT R13 structure ----------------
  const int b = blk;
  const int wave = tid >> 6;
  const int lane = tid & 63;
  const float* xb = xyz + b*3*NN;

  // ---- S1: load my 16 points (coalesced) ----
  float tx[FPT], ty[FPT], tz[FPT];
  #pragma unroll
  for (int j = 0; j < FPT; ++j) {
    int i = tid + j*FTH;
    tx[j] = xb[i]; ty[j] = xb[NN+i]; tz[j] = xb[2*NN+i];
  }
  // ---- S2: block bbox (DPP wave reduce; 0-fill only widens bbox -> perf-only, never wrong) ----
  float mnx = tx[0], mxx = tx[0], mny = ty[0], mxy = ty[0], mnz = tz[0], mxz = tz[0];
  #pragma unroll
  for (int j = 1; j < FPT; ++j) {
    mnx = fminf(mnx, tx[j]); mxx = fmaxf(mxx, tx[j]);
    mny = fminf(mny, ty[j]); mxy = fmaxf(mxy, ty[j]);
    mnz = fminf(mnz, tz[j]); mxz = fmaxf(mxz, tz[j]);
  }
  #define WRED(var, OP) { \
    float s_; \
    s_ = __int_as_float(__builtin_amdgcn_update_dpp(0, __float_as_int(var), 0x111, 0xf, 0xf, true)); var = OP(var, s_); \
    s_ = __int_as_float(__builtin_amdgcn_update_dpp(0, __float_as_int(var), 0x112, 0xf, 0xf, true)); var = OP(var, s_); \
    s_ = __int_as_float(__builtin_amdgcn_update_dpp(0, __float_as_int(var), 0x114, 0xf, 0xf, true)); var = OP(var, s_); \
    s_ = __int_as_float(__builtin_amdgcn_update_dpp(0, __float_as_int(var), 0x118, 0xf, 0xf, true)); var = OP(var, s_); \
    s_ = __int_as_float(__builtin_amdgcn_update_dpp(0, __float_as_int(var), 0x142, 0xf, 0xf, true)); var = OP(var, s_); \
    s_ = __int_as_float(__builtin_amdgcn_update_dpp(0, __float_as_int(var), 0x143, 0xf, 0xf, true)); var = OP(var, s_); }
  WRED(mnx, fminf) WRED(mxx, fmaxf) WRED(mny, fminf) WRED(mxy, fmaxf) WRED(mnz, fminf) WRED(mxz, fmaxf)
  #undef WRED
  if (lane == 63) {
    sred[wave*6+0] = mnx; sred[wave*6+1] = mxx; sred[wave*6+2] = mny;
    sred[wave*6+3] = mxy; sred[wave*6+4] = mnz; sred[wave*6+5] = mxz;
  }
  smi[tid] = 0;                       // zero hist region [0,512)
  __syncthreads();
  #pragma unroll
  for (int w = 0; w < 8; ++w) {
    mnx = fminf(mnx, sred[w*6+0]); mxx = fmaxf(mxx, sred[w*6+1]);
    mny = fminf(mny, sred[w*6+2]); mxy = fmaxf(mxy, sred[w*6+3]);
    mnz = fminf(mnz, sred[w*6+4]); mxz = fmaxf(mxz, sred[w*6+5]);
  }
  const float scx = 8.0f / (mxx - mnx + 1e-12f);
  const float scy = 8.0f / (mxy - mny + 1e-12f);
  const float scz = 8.0f / (mxz - mnz + 1e-12f);
  // ---- S3: histogram by Morton cell ----
  int cells[FPT];
  #pragma unroll
  for (int j = 0; j < FPT; ++j) {
    int qx = min(7, (int)((tx[j] - mnx) * scx));
    int qy = min(7, (int)((ty[j] - mny) * scy));
    int qz = min(7, (int)((tz[j] - mnz) * scz));
    int m = (qx&1) | ((qy&1)<<1) | ((qz&1)<<2)
          | ((qx&2)<<2) | ((qy&2)<<3) | ((qz&2)<<4)
          | ((qx&4)<<4) | ((qy&4)<<5) | ((qz&4)<<6);
    cells[j] = m;
    atomicAdd(&smi[m], 1);
  }
  __syncthreads();
  // ---- S4: inclusive scan over smi[0..511] (Hillis-Steele), exclusive cursors in smi[512..1023] ----
  for (int d = 1; d < 512; d <<= 1) {
    int v = smi[tid];
    int a = (tid >= d) ? smi[tid - d] : 0;
    __syncthreads();
    smi[tid] = v + a;
    __syncthreads();
  }
  {
    int excl = (tid == 0) ? 0 : smi[tid - 1];
    smi[512 + tid] = excl;
  }
  __syncthreads();
  // ---- S5: scatter into sorted order ----
  #pragma unroll
  for (int j = 0; j < FPT; ++j) {
    int pos = atomicAdd(&smi[512 + cells[j]], 1);
    sxyz[pos] = make_float4(tx[j], ty[j], tz[j], 0.0f);
  }
  __syncthreads();
  // ---- S6: reload my contiguous chunk [tid*16, tid*16+16), AABB, dist init ----
  v2f px[FPT/2], py[FPT/2], pz[FPT/2], dist[FPT/2];
  float bx0, bx1, by0, by1, bz0, bz1;
  {
    float4 c0 = sxyz[tid*FPT];
    bx0 = bx1 = c0.x; by0 = by1 = c0.y; bz0 = bz1 = c0.z;
    #pragma unroll
    for (int e = 0; e < FPT; ++e) {
      float4 cc = sxyz[tid*FPT + e];
      ((float*)px)[e] = cc.x; ((float*)py)[e] = cc.y; ((float*)pz)[e] = cc.z;
      ((float*)dist)[e] = 1e10f;
      bx0 = fminf(bx0, cc.x); bx1 = fmaxf(bx1, cc.x);
      by0 = fminf(by0, cc.y); by1 = fmaxf(by1, cc.y);
      bz0 = fminf(bz0, cc.z); bz1 = fmaxf(bz1, cc.z);
    }
  }
  float dmax = 1e10f;
  int   beste = 0;
  float cx = xb[0], cy = xb[NN], cz = xb[2*NN];   // iteration-0 centroid = ORIGINAL point 0
  __syncthreads();
  // ---- main serial loop ----
  for (int it = 1; it < SS; ++it) {
    const int buf = it & 1;
    float gx = fmaxf(fmaxf(bx0 - cx, cx - bx1), 0.0f);
    float gy = fmaxf(fmaxf(by0 - cy, cy - by1), 0.0f);
    float gz = fmaxf(fmaxf(bz0 - cz, cz - bz1), 0.0f);
    float lb = gx*gx + gy*gy; lb = lb + gz*gz;
    if (lb * 0.99999f < dmax) {
      v2f cx2 = {cx, cx}, cy2 = {cy, cy}, cz2 = {cz, cz};
      v2f vmax = {-1.0f, -1.0f};
      #pragma unroll
      for (int j = 0; j < FPT/2; ++j) {
        v2f dx = px[j] - cx2, dy = py[j] - cy2, dz = pz[j] - cz2;
        v2f d = dx*dx + dy*dy;
        d = d + dz*dz;
        v2f nd = __builtin_elementwise_min(dist[j], d);
        dist[j] = nd;
        vmax = __builtin_elementwise_max(vmax, nd);
      }
      float mloc = fmaxf(vmax.x, vmax.y);
      int ce[FPT/2];
      #pragma unroll
      for (int j = 0; j < FPT/2; ++j) {
        int c = 0x7FFFFFFF;
        if (dist[j].y == mloc) c = 2*j + 1;
        if (dist[j].x == mloc) c = 2*j;
        ce[j] = c;
      }
      #pragma unroll
      for (int st = FPT/4; st >= 1; st >>= 1) {
        #pragma unroll
        for (int j = 0; j < st; ++j) ce[j] = ce[j] < ce[j+st] ? ce[j] : ce[j+st];
      }
      dmax = mloc;
      beste = ce[0];
    }
    // R18 wave argmax: f32 max ladder (lane63 = wave max) -> bcast -> ballot -> lowest lane -> readlane idx.
    // Exact: fmax/DPP propagate operand bits; lowest matching lane = smallest (tid<<4)+beste among ties.
    float wm = dmax;
    #define FPS_MAXR(ctrl) { \
      float s_ = __int_as_float(__builtin_amdgcn_update_dpp(0, __float_as_int(wm), ctrl, 0xf, 0xf, true)); \
      wm = fmaxf(wm, s_); }
    FPS_MAXR(0x111)  // row_shr:1
    FPS_MAXR(0x112)  // row_shr:2
    FPS_MAXR(0x114)  // row_shr:4
    FPS_MAXR(0x118)  // row_shr:8
    FPS_MAXR(0x142)  // row_bcast:15
    FPS_MAXR(0x143)  // row_bcast:31
    #undef FPS_MAXR
    wm = __int_as_float(__builtin_amdgcn_readlane(__float_as_int(wm), 63));  // wave max to all lanes
    unsigned long long em = __ballot(dmax == wm);             // nonempty (max came from some lane)
    int lw = (int)__ffsll((unsigned long long)em) - 1;        // lowest matching lane
    int bi_w = __builtin_amdgcn_readlane((tid << 4) + beste, lw);
    if (lane == 63) skey[buf][wave] = ((unsigned long long)__float_as_uint(wm) << 32) | (unsigned)~bi_w;
    __syncthreads();
    const ulonglong2* kp = (const ulonglong2*)&skey[buf][0];
    ulonglong2 k01 = kp[0], k23 = kp[1], k45 = kp[2], k67 = kp[3];
    unsigned long long m0 = k01.x > k01.y ? k01.x : k01.y;
    unsigned long long m1 = k23.x > k23.y ? k23.x : k23.y;
    unsigned long long m2 = k45.x > k45.y ? k45.x : k45.y;
    unsigned long long m3 = k67.x > k67.y ? k67.x : k67.y;
    unsigned long long ma = m0 > m1 ? m0 : m1;
    unsigned long long mb = m2 > m3 ? m2 : m3;
    unsigned long long mk = ma > mb ? ma : mb;
    int mi = (int)(~(unsigned)mk);
    float4 c = sxyz[mi];
    if (tid == 0) smi[it] = mi;
    cx = c.x; cy = c.y; cz = c.z;
  }
  __syncthreads();
  // epilogue: it=0 from ORIGINAL point 0; others from sorted winner history
  for (int it = tid; it < SS; it += FTH) {
    float x, y, z;
    if (it == 0) { x = xb[0]; y = xb[NN]; z = xb[2*NN]; }
    else { float4 c = sxyz[smi[it]]; x = c.x; y = c.y; z = c.z; }
    out_newxyz[(b*3+0)*SS + it] = x;
    out_newxyz[(b*3+1)*SS + it] = y;
    out_newxyz[(b*3+2)*SS + it] = z;
    nxt[(b*SS+it)*3+0] = x; nxt[(b*SS+it)*3+1] = y; nxt[(b*SS+it)*3+2] = z;
  }
  if (tid == 0) atomicAdd(spin_flag, 1);   // release spinners
}

// ---------------- KNN fused, 512 thr = 8 waves; each wave scans 1/8; 8-way stable merge ----------------
#define TILE 2048
#define KTH 512
__global__ __launch_bounds__(KTH) void knn_kernel(
    const float* __restrict__ query_t, // [B,S,3]
    const float* __restrict__ cand1,   // [B,3,NN]
    const float* __restrict__ cand2,   // [B,3,SS]
    int* __restrict__ out1,            // [B,S,K]
    int* __restrict__ out2)            // [B,S,K]
{
  #pragma clang fp contract(off)
  __shared__ float4 sc[TILE];            // 32 KB
  __shared__ float  smd[8*64*17];        // per-wave top-16 dists (pad 17) ~34.8 KB
  __shared__ int    smj[8*64*17];        // per-wave top-16 idxs
  const int blocksPerB = SS/64;          // 32
  const int half = blockIdx.x >> 7;      // 0: vs xyz, 1: self
  const int blk = blockIdx.x & 127;
  const float* cand = half ? cand2 : cand1;
  const int Nc = half ? SS : NN;
  int* outidx = half ? out2 : out1;
  const int b = blk / blocksPerB;
  const int q0 = (blk % blocksPerB)*64;
  const int wave = threadIdx.x >> 6, lane = threadIdx.x & 63;
  const int s = q0 + lane;
  const float qx = query_t[(b*SS+s)*3+0];
  const float qy = query_t[(b*SS+s)*3+1];
  const float qz = query_t[(b*SS+s)*3+2];
  float sq = qx*qx + qy*qy; sq = sq + qz*qz;
  float d16[16]; int i16[16];
  #pragma unroll
  for (int j = 0; j < 16; ++j) { d16[j] = 1e30f; i16[j] = 0x7FFFFFFF; }
  const float* cb = cand + b*3*Nc;
  const int QL = TILE/8;                 // 256 candidates per wave per tile
  for (int base = 0; base < Nc; base += TILE) {
    __syncthreads();
    for (int j = threadIdx.x; j < TILE; j += KTH) {
      float x = cb[base+j], y = cb[Nc+base+j], z = cb[2*Nc+base+j];
      float pp = x*x + y*y; pp = pp + z*z;
      sc[j] = make_float4(x, y, z, pp);
    }
    __syncthreads();
    const int lo = wave*QL, hi = lo + QL;
    for (int j = lo; j < hi; ++j) {
      float4 c = sc[j];
      float qp = qx*c.x + qy*c.y; qp = qp + qz*c.z;
      float d2 = (sq + c.w) - 2.0f*qp;
      if (d2 < d16[15]) {
        d16[15] = d2; i16[15] = base + j;
        #pragma unroll
        for (int t = 15; t > 0; --t) {
          if (d16[t] < d16[t-1]) {
            float td = d16[t]; d16[t] = d16[t-1]; d16[t-1] = td;
            int   ti = i16[t]; i16[t] = i16[t-1]; i16[t-1] = ti;
          }
        }
      }
    }
  }
  const int off = (wave*64 + lane)*17;
  #pragma unroll
  for (int j = 0; j < 16; ++j) { smd[off+j] = d16[j]; smj[off+j] = i16[j]; }
  __syncthreads();
  if (wave == 0) {
    // 8-way stable merge: tie-break on smaller index = stable lax.top_k semantics
    int p[8] = {0,0,0,0,0,0,0,0};
    for (int o = 0; o < 16; ++o) {
      float bd = 3e38f; int bi = 0x7FFFFFFF, bw = 0;
      #pragma unroll
      for (int w = 0; w < 8; ++w) {
        float d = smd[(w*64+lane)*17 + p[w]];
        int   i = smj[(w*64+lane)*17 + p[w]];
        if (d < bd || (d == bd && i < bi)) { bd = d; bi = i; bw = w; }
      }
      p[bw]++;
      outidx[(b*SS+s)*KK + o] = bi;
    }
  }
}

// ---------------- Transition-down conv + stats + max over K (ptst gather, coalesced) ----------------
__global__ __launch_bounds__(128) void td_kernel(
    const float* __restrict__ ptst,    // [B,N,64] point-major
    const float* __restrict__ xyz,     // [B,3,N]
    const float* __restrict__ newxyz,  // [B,3,S]
    const int* __restrict__ gidx,      // [B,S,K]
    const float* __restrict__ td_w,    // [128,67]
    const float* __restrict__ td_b,    // [128]
    float* __restrict__ ymax,          // [B*S,128]
    float* __restrict__ psum,          // [B*S,128]
    float* __restrict__ psq)
{
  const int bs = blockIdx.x;
  const int b = bs >> 11, s = bs & (SS-1);
  const int t = threadIdx.x;
  __shared__ int gi[KK];
  __shared__ float g[67*17];           // stride 17: conflict-free writes
  if (t < KK) gi[t] = gidx[bs*KK + t];
  __syncthreads();
  // features 0..63: per neighbor, 64 consecutive floats (coalesced 256B rows)
  #pragma unroll
  for (int base = 0; base < 1024; base += 128) {
    int idx = base + t;
    int i = idx & 63, k = idx >> 6;
    g[i*17 + k] = ptst[(b*NN + gi[k])*64 + i];
  }
  // xyz channels 64..66 (48 scattered reads)
  if (t < 48) {
    int c = t >> 4, k = t & 15;
    g[(64+c)*17 + k] = xyz[(b*3+c)*NN + gi[k]] - newxyz[(b*3+c)*SS + s];
  }
  __syncthreads();
  float acc[KK];
  #pragma unroll
  for (int k = 0; k < KK; ++k) acc[k] = 0.0f;
  const float* wrow = td_w + t*67;
  for (int i = 0; i < 67; ++i) {
    float w = wrow[i];
    #pragma unroll
    for (int k = 0; k < KK; ++k) acc[k] = fmaf(w, g[i*17 + k], acc[k]);
  }
  float bias = td_b[t];
  float mx = -1e30f, s1 = 0.f, s2 = 0.f;
  #pragma unroll
  for (int k = 0; k < KK; ++k) {
    float y = acc[k] + bias;
    mx = fmaxf(mx, y);
    s1 += y;
    s2 = fmaf(y, y, s2);
  }
  ymax[bs*128 + t] = mx;             // coalesced
  psum[bs*128 + t] = s1;             // coalesced
  psq [bs*128 + t] = s2;             // coalesced
}

// ---------------- bn_partial + fused bn_final (last-block trick; counter zeroed by fps launch) ----------------
__global__ __launch_bounds__(256) void bn_partial(
    const float* __restrict__ psum, const float* __restrict__ psq,
    float* __restrict__ part1, float* __restrict__ part2,
    const float* __restrict__ gamma, const float* __restrict__ beta,
    float* __restrict__ scale, float* __restrict__ bias,
    int* __restrict__ counter)
{
  const int blk = blockIdx.x, t = threadIdx.x;
  const int c = t & 127, half = t >> 7;
  const float* ps = psum + (blk*64 + half*32)*128;
  const float* pq = psq  + (blk*64 + half*32)*128;
  float s1 = 0.f, s2 = 0.f;
  for (int r = 0; r < 32; ++r) { s1 += ps[r*128 + c]; s2 += pq[r*128 + c]; }
  __shared__ float sh1[256], sh2[256];
  __shared__ int s_last;
  sh1[t] = s1; sh2[t] = s2;
  __syncthreads();
  if (t < 128) {
    part1[blk*128 + t] = sh1[t] + sh1[t+128];
    part2[blk*128 + t] = sh2[t] + sh2[t+128];
  }
  // release: make part writes visible, then count this block done
  __syncthreads();
  __threadfence();
  if (t == 0) s_last = (atomicAdd(counter, 1) == 127) ? 1 : 0;
  __syncthreads();
  if (!s_last) return;
  __threadfence();    // acquire: all other blocks' part writes now visible
  // final reduce: thread t handles channel c over half the 128 part rows
  float f1 = 0.f, f2 = 0.f;
  for (int j = half*64; j < half*64 + 64; ++j) {
    f1 += part1[j*128 + c];
    f2 += part2[j*128 + c];
  }
  sh1[t] = f1; sh2[t] = f2;
  __syncthreads();
  if (t < 128) {
    float a1 = sh1[t] + sh1[t+128];
    float a2 = sh2[t] + sh2[t+128];
    const float n = (float)(BB*SS*KK);
    float mean = a1/n;
    float var  = a2/n - mean*mean;
    float sc = gamma[t] / sqrtf(var + 1e-5f);
    scale[t] = sc;
    bias[t]  = beta[t] - mean*sc;
  }
}

// ---------------- r1_first: fused td_final + r1 (i=0) ----------------
__global__ __launch_bounds__(128) void r1_first(
    const float* __restrict__ ymax,   // [B*S,128]
    const float* __restrict__ scale, const float* __restrict__ bias,
    const float* __restrict__ bw, const float* __restrict__ bb,   // [32,128],[32]
    const float* __restrict__ qw,                                 // [96,32]
    float* __restrict__ pts,          // [B*S,128] (written here)
    float* __restrict__ qkv)
{
  const int bs = blockIdx.x;
  const int t = threadIdx.x;
  __shared__ float pcol[128];
  __shared__ float p[32];
  float v = fmaxf(fmaf(ymax[bs*128 + t], scale[t], bias[t]), 0.0f);
  pts[bs*128 + t] = v;               // materialize pts for r2's residual +=
  pcol[t] = v;
  __syncthreads();
  if (t < 32) {
    float acc = 0.f;
    const float* w = bw + t*128;
    for (int j = 0; j < 128; ++j) acc = fmaf(w[j], pcol[j], acc);
    p[t] = acc + bb[t];
  }
  __syncthreads();
  if (t < 96) {
    float acc = 0.f;
    const float* w = qw + t*32;
    #pragma unroll
    for (int j = 0; j < 32; ++j) acc = fmaf(w[j], p[j], acc);
    qkv[bs*96 + t] = acc;            // coalesced
  }
}

// ---------------- Res block part 1 (pts [B*S,128], qkv [B*S,96]) ----------------
__global__ __launch_bounds__(128) void r1_kernel(
    const float* __restrict__ pts,
    const float* __restrict__ bw, const float* __restrict__ bb,   // [32,128],[32]
    const float* __restrict__ qw,                                 // [96,32]
    float* __restrict__ qkv)
{
  const int bs = blockIdx.x;
  const int t = threadIdx.x;
  __shared__ float pcol[128];
  __shared__ float p[32];
  pcol[t] = pts[bs*128 + t];           // coalesced
  __syncthreads();
  if (t < 32) {
    float acc = 0.f;
    const float* w = bw + t*128;
    for (int j = 0; j < 128; ++j) acc = fmaf(w[j], pcol[j], acc);
    p[t] = acc + bb[t];
  }
  __syncthreads();
  if (t < 96) {
    float acc = 0.f;
    const float* w = qw + t*32;
    #pragma unroll
    for (int j = 0; j < 32; ++j) acc = fmaf(w[j], p[j], acc);
    qkv[bs*96 + t] = acc;              // coalesced
  }
}

// ---------------- Res block part 2; outT!=null => write final transposed to [B,128,S] (skip pts) ----------------
__global__ __launch_bounds__(128) void r2_kernel(
    const float* __restrict__ qkv,
    const float* __restrict__ newxyz, // [B,3,S]
    const int* __restrict__ sgidx,    // [B,S,K]
    const float* __restrict__ pw1, const float* __restrict__ pb1,  // [64,3],[64]
    const float* __restrict__ pw2, const float* __restrict__ pb2,  // [32,64],[32]
    const float* __restrict__ aw1, const float* __restrict__ ab1,  // [128,32],[128]
    const float* __restrict__ aw2, const float* __restrict__ ab2,  // [32,128],[32]
    const float* __restrict__ fw,  const float* __restrict__ fb,   // [128,32],[128]
    float* __restrict__ pts,          // [B*S,128]  (+= when outT==null)
    float* __restrict__ outT)         // [B,128,S] or null
{
  const int bs = blockIdx.x;
  const int b = bs >> 11, s = bs & (SS-1);
  const int t = threadIdx.x;
  __shared__ int sgi[KK];
  __shared__ float qv[32];
  __shared__ float kn[32*17], vn[32*17];   // stride 17: conflict-free
  __shared__ float gx[3*KK];
  __shared__ float h1[64*KK];
  __shared__ float x2[32*KK];
  __shared__ float a1[128*17];             // stride 17: kills 16-way write conflicts
  __shared__ float simb[32*KK];
  __shared__ float agg[32];
  if (t < KK) sgi[t] = sgidx[bs*KK + t];
  __syncthreads();
  if (t < 32) qv[t] = qkv[bs*96 + t];
  // c-major gather: each wave reads 2 neighbor rows x 32 consecutive floats (coalesced)
  for (int idx = t; idx < 32*KK; idx += 128) {
    int k = idx >> 5, c = idx & 31;
    int base = (b*SS + sgi[k])*96;
    kn[c*17+k] = qkv[base + 32 + c];
    vn[c*17+k] = qkv[base + 64 + c];
  }
  if (t < 3*KK) {
    int c = t >> 4, k = t & 15;
    gx[t] = newxyz[(b*3+c)*SS + s] - newxyz[(b*3+c)*SS + sgi[k]];
  }
  __syncthreads();
  for (int idx = t; idx < 64*KK; idx += 128) {
    int c = idx >> 4, k = idx & 15;
    float acc = 0.f;
    #pragma unroll
    for (int j = 0; j < 3; ++j) acc = fmaf(pw1[c*3+j], gx[j*KK+k], acc);
    h1[idx] = fmaxf(acc + pb1[c], 0.0f);
  }
  __syncthreads();
  for (int idx = t; idx < 32*KK; idx += 128) {
    int c = idx >> 4, k = idx & 15;
    float acc = 0.f;
    const float* w = pw2 + c*64;
    for (int j = 0; j < 64; ++j) acc = fmaf(w[j], h1[j*KK+k], acc);
    float r = acc + pb2[c];
    x2[idx] = (qv[c] - kn[c*17+k]) + r;   // qk_rel + rel
    vn[c*17+k] = vn[c*17+k] + r;          // v + rel
  }
  __syncthreads();
  {
    float acc[KK];
    #pragma unroll
    for (int k = 0; k < KK; ++k) acc[k] = 0.f;
    const float* w = aw1 + t*32;
    for (int j = 0; j < 32; ++j) {
      float wv = w[j];
      #pragma unroll
      for (int k = 0; k < KK; ++k) acc[k] = fmaf(wv, x2[j*KK+k], acc[k]);
    }
    float bv = ab1[t];
    #pragma unroll
    for (int k = 0; k < KK; ++k) a1[t*17+k] = fmaxf(acc[k] + bv, 0.0f);
  }
  __syncthreads();
  for (int idx = t; idx < 32*KK; idx += 128) {
    int c = idx >> 4, k = idx & 15;
    float acc = 0.f;
    const float* w = aw2 + c*128;
    for (int j = 0; j < 128; ++j) acc = fmaf(w[j], a1[j*17+k], acc);
    simb[idx] = acc + ab2[c];
  }
  __syncthreads();
  if (t < 32) {
    float m = -1e30f;
    #pragma unroll
    for (int k = 0; k < KK; ++k) m = fmaxf(m, simb[t*KK+k]);
    float sum = 0.f;
    float e[KK];
    #pragma unroll
    for (int k = 0; k < KK; ++k) { e[k] = __expf(simb[t*KK+k] - m); sum += e[k]; }
    float inv = 1.0f / sum;
    float a = 0.f;
    #pragma unroll
    for (int k = 0; k < KK; ++k) a = fmaf(e[k]*inv, vn[t*17+k], a);
    agg[t] = a;
  }
  __syncthreads();
  {
    float acc = 0.f;
    const float* w = fw + t*32;
    #pragma unroll
    for (int j = 0; j < 32; ++j) acc = fmaf(w[j], agg[j], acc);
    float val = pts[bs*128 + t] + (acc + fb[t]);
    if (outT) outT[(b*128 + t)*SS + s] = val;    // final layer: direct transposed store
    else      pts[bs*128 + t] = val;             // coalesced
  }
}

extern "C" void kernel_launch(void* const* d_in, const int* in_sizes, int n_in,
                              void* d_out, int out_size, void* d_ws, size_t ws_size,
                              hipStream_t stream) {
  const float* xyz      = (const float*)d_in[0];
  const float* points   = (const float*)d_in[1];
  const float* td_w     = (const float*)d_in[2];
  const float* td_b     = (const float*)d_in[3];
  const float* td_gamma = (const float*)d_in[4];
  const float* td_beta  = (const float*)d_in[5];
  const float* bw  = (const float*)d_in[6];
  const float* bb  = (const float*)d_in[7];
  const float* qw  = (const float*)d_in[8];
  const float* pw1 = (const float*)d_in[9];
  const float* pb1 = (const float*)d_in[10];
  const float* pw2 = (const float*)d_in[11];
  const float* pb2 = (const float*)d_in[12];
  const float* aw1 = (const float*)d_in[13];
  const float* ab1 = (const float*)d_in[14];
  const float* aw2 = (const float*)d_in[15];
  const float* ab2 = (const float*)d_in[16];
  const float* fw  = (const float*)d_in[17];
  const float* fb  = (const float*)d_in[18];
  float* out = (float*)d_out;
  float* out_newxyz = out;                 // [B,3,S]
  float* out_pts    = out + BB*3*SS;       // [B,128,S]

  char* w = (char*)d_ws;
  float* nxt    = (float*)w; w += BB*SS*3*sizeof(float);
  int*   gidx   = (int*)w;   w += BB*SS*KK*sizeof(int);
  int*   sgidx  = (int*)w;   w += BB*SS*KK*sizeof(int);
  float* ymax   = (float*)w; w += BB*128*SS*sizeof(float);
  float* psum   = (float*)w; w += 128*BB*SS*sizeof(float);
  float* psq    = (float*)w; w += 128*BB*SS*sizeof(float);
  float* part1  = (float*)w; w += 128*128*sizeof(float);
  float* part2  = (float*)w; w += 128*128*sizeof(float);
  float* bnscale= (float*)w; w += 256*sizeof(float);
  float* bnbias = (float*)w; w += 256*sizeof(float);
  float* pts    = (float*)w; w += BB*128*SS*sizeof(float);
  float* qkv    = (float*)w; w += BB*96*SS*sizeof(float);
  float* ptst   = (float*)w; w += BB*NN*64*sizeof(float);   // [B,N,64]
  int*   flags  = (int*)w;   w += 256;   // [0]=spinner release, [8]=bn counter (zeroed by fps launch)

  fps_kernel<<<BB + TRB + SPB, FTH, 0, stream>>>(xyz, points, out_newxyz, nxt, ptst, flags);
  knn_kernel<<<2*BB*(SS/64), KTH, 0, stream>>>(nxt, xyz, out_newxyz, gidx, sgidx);
  td_kernel<<<BB*SS, 128, 0, stream>>>(ptst, xyz, out_newxyz, gidx, td_w, td_b, ymax, psum, psq);
  bn_partial<<<128, 256, 0, stream>>>(psum, psq, part1, part2,
      td_gamma, td_beta, bnscale, bnbias, &flags[8]);
  // i = 0: r1 fused with td_final (writes pts from ymax)
  r1_first<<<BB*SS, 128, 0, stream>>>(ymax, bnscale, bnbias, bw, bb, qw, pts, qkv);
  r2_kernel<<<BB*SS, 128, 0, stream>>>(qkv, out_newxyz, sgidx,
      pw1, pb1, pw2, pb2, aw1, ab1, aw2, ab2, fw, fb, pts, nullptr);
  // i = 1: final r2 writes directly to out_pts transposed (transpose_out folded in)
  r1_kernel<<<BB*SS, 128, 0, stream>>>(pts, bw + 32*128, bb + 32, qw + 96*32, qkv);
  r2_kernel<<<BB*SS, 128, 0, stream>>>(qkv, out_newxyz, sgidx,
      pw1 + 64*3, pb1 + 64, pw2 + 32*64, pb2 + 32,
      aw1 + 128*32, ab1 + 128, aw2 + 32*128, ab2 + 32,
      fw + 128*32, fb + 128, pts, out_pts);
}